// Round 8
// baseline (273.288 us; speedup 1.0000x reference)
//
#include <hip/hip_runtime.h>
#include <math.h>

// Problem constants
#define BATCH 4
#define CIN   256
#define CCH   128      // Cout
#define HW    4096     // 64*64
#define CQK   16

using short8   = __attribute__((ext_vector_type(8))) short;
using floatx4  = __attribute__((ext_vector_type(4))) float;
using floatx16 = __attribute__((ext_vector_type(16))) float;
using uint4v   = __attribute__((ext_vector_type(4))) unsigned int;

__device__ __forceinline__ float fast_tanh(float x) {
    float e = __expf(2.0f * x);
    return 1.0f - __fdividef(2.0f, e + 1.0f);
}

__device__ __forceinline__ unsigned short f2bf(float f) {
    unsigned u = __float_as_uint(f);
    u += 0x7fff + ((u >> 16) & 1);   // RNE
    return (unsigned short)(u >> 16);
}

__device__ __forceinline__ float bf2f(unsigned short u) {
    return __uint_as_float(((unsigned)u) << 16);
}

// C/D row map for mfma_f32_32x32x16: row = (r&3) + 8*(r>>2) + 4*hi, col = lane&31
#define ROWMAP(r, hi) (((r) & 3) + (((r) >> 2) << 3) + ((hi) << 2))

#define XTP_ROW   (66 * 256)          // shorts per padded row
#define XTP_BATCH (66 * 66 * 256)     // shorts per batch

// ---------------------------------------------------------------------------
// 0) transpose x [b][ci][y][x] fp32 -> xTp [b][y+1][x+1][ci] bf16, with halo
// grid(4 ci-tiles, 64 y, 4 b), block 256
// ---------------------------------------------------------------------------
__global__ __launch_bounds__(256) void xt_prep_kernel(
        const float* __restrict__ x, unsigned short* __restrict__ xTp) {
    __shared__ unsigned short lds[64][72];
    const int tid = threadIdx.x;
    const int ci0 = blockIdx.x * 64, yr = blockIdx.y, b = blockIdx.z;
    const int cir = tid >> 2, xc = tid & 3;
    const float* xp = x + (((b << 8) + ci0 + cir) << 12) + (yr << 6) + xc * 16;
#pragma unroll
    for (int j = 0; j < 4; ++j) {
        float4 v = *(const float4*)(xp + j * 4);
        int xi = xc * 16 + j * 4;
        lds[xi + 0][cir] = f2bf(v.x);
        lds[xi + 1][cir] = f2bf(v.y);
        lds[xi + 2][cir] = f2bf(v.z);
        lds[xi + 3][cir] = f2bf(v.w);
    }
    const short8 z8 = (short8){0,0,0,0,0,0,0,0};
    if (tid < 16) {
        int col = (tid >> 3) ? 65 : 0;
        int part = tid & 7;
        *(short8*)(xTp + b * XTP_BATCH + (yr + 1) * XTP_ROW + col * 256 +
                   ci0 + part * 8) = z8;
    }
    if (yr == 0 || yr == 63) {
        int row = (yr == 0) ? 0 : 65;
        for (int e = tid; e < 528; e += 256) {
            int xi = e >> 3, part = e & 7;
            *(short8*)(xTp + b * XTP_BATCH + row * XTP_ROW + xi * 256 +
                       ci0 + part * 8) = z8;
        }
    }
    __syncthreads();
    const int xr = tid >> 2, part = tid & 3;
    unsigned short* dst = xTp + b * XTP_BATCH + (yr + 1) * XTP_ROW +
                          (xr + 1) * 256 + ci0 + part * 16;
    *(short8*)(dst + 0) = *(const short8*)&lds[xr][part * 16 + 0];
    *(short8*)(dst + 8) = *(const short8*)&lds[xr][part * 16 + 8];
}

// ---------------------------------------------------------------------------
// 1) Fused weight prep (conv + qkv weights)
// ---------------------------------------------------------------------------
__global__ __launch_bounds__(256) void prep_kernel(
        const float* __restrict__ w,
        const float* __restrict__ qw, const float* __restrict__ qb,
        const float* __restrict__ kw, const float* __restrict__ kb,
        const float* __restrict__ vw, const float* __restrict__ vb,
        unsigned short* __restrict__ Wb2, unsigned short* __restrict__ Wqkv,
        float* __restrict__ biasAll) {
    if (blockIdx.x < 1152) {
        int o = blockIdx.x * 256 + threadIdx.x;          // < 294912
        int s   = o & 31;
        int co  = (o >> 5) & 127;
        int cc  = (o >> 12) & 7;
        int tap = o >> 15;
        int ci  = (cc << 5) + s;
        Wb2[o] = f2bf(w[co * 2304 + ci * 9 + tap]);
    } else {
        int idx = (blockIdx.x - 1152) * 256 + threadIdx.x;   // < 20480
        int o = idx >> 7, c = idx & 127;
        float wv = (o < 16) ? qw[(o << 7) + c]
                 : (o < 32) ? kw[((o - 16) << 7) + c]
                            : vw[((o - 32) << 7) + c];
        Wqkv[idx] = f2bf(wv);
        if (idx < 160)
            biasAll[idx] = (idx < 16) ? qb[idx] : (idx < 32) ? kb[idx - 16] : vb[idx - 32];
    }
}

// ---------------------------------------------------------------------------
// 2) Conv implicit GEMM, bf16 MFMA 16x16x32 — LDS-free, barrier-free.
//    Wave = 32 co x 16 px. Block = 128 co x 16 px (one x-quarter of a row).
// grid(4, 64, 4) = 1024 blocks, block 256 -> 4 blocks/CU.
// ---------------------------------------------------------------------------
__global__ __launch_bounds__(256) void conv_mfma_kernel(
        const unsigned short* __restrict__ xTp, const unsigned short* __restrict__ Wb2,
        float* __restrict__ y) {
    const int tid = threadIdx.x;
    const int w = tid >> 6, lane = tid & 63, l15 = lane & 15, quad = lane >> 4;
    const int x0 = blockIdx.x * 16, yr = blockIdx.y, b = blockIdx.z;

    floatx4 acc[2];
    acc[0] = (floatx4){0.f, 0.f, 0.f, 0.f};
    acc[1] = (floatx4){0.f, 0.f, 0.f, 0.f};

    const unsigned short* xb = xTp + b * XTP_BATCH + yr * XTP_ROW;
    const int aco0 = (w << 5) + l15;

#pragma unroll
    for (int ky = 0; ky < 3; ++ky) {
#pragma unroll
        for (int kx = 0; kx < 3; ++kx) {
            const unsigned short* arow = Wb2 + ((ky * 3 + kx) << 15);
            const unsigned short* brow = xb + ky * XTP_ROW + (x0 + kx) * 256;
#pragma unroll
            for (int cc = 0; cc < 8; ++cc) {
                short8 a0 = *(const short8*)(arow + (((cc << 7) + aco0) << 5) + quad * 8);
                short8 a1 = *(const short8*)(arow + (((cc << 7) + aco0 + 16) << 5) + quad * 8);
                short8 b0 = *(const short8*)(brow + (l15 << 8) + (cc << 5) + quad * 8);
                acc[0] = __builtin_amdgcn_mfma_f32_16x16x32_bf16(a0, b0, acc[0], 0, 0, 0);
                acc[1] = __builtin_amdgcn_mfma_f32_16x16x32_bf16(a1, b0, acc[1], 0, 0, 0);
            }
        }
    }

    const int px = x0 + l15;
#pragma unroll
    for (int ms = 0; ms < 2; ++ms)
#pragma unroll
        for (int r = 0; r < 4; ++r) {
            int co = (w << 5) + ms * 16 + quad * 4 + r;
            y[(((b << 7) + co) << 12) + (yr << 6) + px] = acc[ms][r];
        }
}

// ---------------------------------------------------------------------------
// 3) BN stats per channel -> fused scale/shift. grid(128), block 256
// ---------------------------------------------------------------------------
__global__ __launch_bounds__(256) void bn_stats_kernel(
        const float* __restrict__ y, const float* __restrict__ gamma,
        const float* __restrict__ beta, float* __restrict__ scale,
        float* __restrict__ shift) {
    const int c = blockIdx.x, tid = threadIdx.x;
    float s = 0.f, q = 0.f;
    for (int i = tid; i < BATCH * HW; i += 256) {
        float v = y[((((i >> 12) << 7) + c) << 12) + (i & 4095)];
        s += v; q += v * v;
    }
    for (int off = 32; off; off >>= 1) {
        s += __shfl_down(s, off);
        q += __shfl_down(q, off);
    }
    __shared__ float ls[4], lq[4];
    if ((tid & 63) == 0) { ls[tid >> 6] = s; lq[tid >> 6] = q; }
    __syncthreads();
    if (tid == 0) {
        float S = ls[0] + ls[1] + ls[2] + ls[3];
        float Q = lq[0] + lq[1] + lq[2] + lq[3];
        float mean = S * (1.f / 16384.f);
        float var  = Q * (1.f / 16384.f) - mean * mean;
        float rstd = rsqrtf(var + 1e-5f);
        float sc = gamma[c] * rstd;
        scale[c] = sc;
        shift[c] = beta[c] - mean * sc;
    }
}

// ---------------------------------------------------------------------------
// 4) BN apply + ReLU -> featB [b][c][n] and fT [b][n][c] via LDS transpose.
// grid(2, 64, 4), block 256
// ---------------------------------------------------------------------------
__global__ __launch_bounds__(256) void bn_apply_kernel(
        const float* __restrict__ y, const float* __restrict__ scale,
        const float* __restrict__ shift, unsigned short* __restrict__ featB,
        unsigned short* __restrict__ fT) {
    __shared__ unsigned short lds[64][72];
    const int tid = threadIdx.x;
    const int c0 = blockIdx.x * 64, n0 = blockIdx.y * 64, b = blockIdx.z;
    const int cir = tid >> 2, xc = tid & 3;
    const float sc = scale[c0 + cir], sh = shift[c0 + cir];
    const float* yp = y + (((b << 7) + c0 + cir) << 12) + n0 + xc * 16;
    unsigned short* fp = featB + (((b << 7) + c0 + cir) << 12) + n0 + xc * 16;
#pragma unroll
    for (int j = 0; j < 4; ++j) {
        float4 v = *(const float4*)(yp + j * 4);
        ushort4 o;
        o.x = f2bf(fmaxf(fmaf(v.x, sc, sh), 0.f));
        o.y = f2bf(fmaxf(fmaf(v.y, sc, sh), 0.f));
        o.z = f2bf(fmaxf(fmaf(v.z, sc, sh), 0.f));
        o.w = f2bf(fmaxf(fmaf(v.w, sc, sh), 0.f));
        *(ushort4*)(fp + j * 4) = o;
        int ni = xc * 16 + j * 4;
        lds[ni + 0][cir] = o.x;
        lds[ni + 1][cir] = o.y;
        lds[ni + 2][cir] = o.z;
        lds[ni + 3][cir] = o.w;
    }
    __syncthreads();
    const int nr = tid >> 2, part = tid & 3;
    unsigned short* dst = fT + (((b << 12) + n0 + nr) << 7) + c0 + part * 16;
    *(short8*)(dst + 0) = *(const short8*)&lds[nr][part * 16 + 0];
    *(short8*)(dst + 8) = *(const short8*)&lds[nr][part * 16 + 8];
}

// ---------------------------------------------------------------------------
// 5) CAM energy via MFMA, split-K 64 (K=64/block), plain partial stores.
// grid(64, 4), block 256 -> ep[kc][b][c][d] fp32, 256 blocks.
// ---------------------------------------------------------------------------
__global__ __launch_bounds__(256) void cam_energy_mfma_kernel(
        const unsigned short* __restrict__ featB, float* __restrict__ ep) {
    const int b = blockIdx.y, kc = blockIdx.x, tid = threadIdx.x;
    const int wv = tid >> 6, l31 = tid & 31, hi = (tid >> 5) & 1;
    floatx16 acc[4];
#pragma unroll
    for (int t = 0; t < 4; ++t)
#pragma unroll
        for (int r = 0; r < 16; ++r) acc[t][r] = 0.f;

    for (int s = 0; s < 4; ++s) {
        const int k0 = (kc << 6) + (s << 4) + (hi << 3);
        short8 fr = *(const short8*)&featB[(((b << 7) + (wv << 5) + l31) << 12) + k0];
        short8 fc0 = *(const short8*)&featB[(((b << 7) +  0 + l31) << 12) + k0];
        short8 fc1 = *(const short8*)&featB[(((b << 7) + 32 + l31) << 12) + k0];
        short8 fc2 = *(const short8*)&featB[(((b << 7) + 64 + l31) << 12) + k0];
        short8 fc3 = *(const short8*)&featB[(((b << 7) + 96 + l31) << 12) + k0];
        acc[0] = __builtin_amdgcn_mfma_f32_32x32x16_bf16(fr, fc0, acc[0], 0, 0, 0);
        acc[1] = __builtin_amdgcn_mfma_f32_32x32x16_bf16(fr, fc1, acc[1], 0, 0, 0);
        acc[2] = __builtin_amdgcn_mfma_f32_32x32x16_bf16(fr, fc2, acc[2], 0, 0, 0);
        acc[3] = __builtin_amdgcn_mfma_f32_32x32x16_bf16(fr, fc3, acc[3], 0, 0, 0);
    }
#pragma unroll
    for (int t = 0; t < 4; ++t)
#pragma unroll
        for (int r = 0; r < 16; ++r) {
            int c = (wv << 5) + ROWMAP(r, hi);
            int d = (t << 5) + l31;
            ep[(((kc << 2) + b) << 14) + (c << 7) + d] = acc[t][r];
        }
}

// 6) CAM attn: sum 64 partials, attnB = bf16(tanh(rowmax - e)). grid(128,4)
__global__ __launch_bounds__(128) void cam_attn_kernel(
        const float* __restrict__ ep, unsigned short* __restrict__ attnB) {
    const int b = blockIdx.y, c = blockIdx.x, tid = threadIdx.x;
    float v = 0.f;
#pragma unroll 8
    for (int s = 0; s < 64; ++s)
        v += ep[(((s << 2) + b) << 14) + (c << 7) + tid];
    float m = v;
    for (int off = 32; off; off >>= 1) m = fmaxf(m, __shfl_down(m, off));
    __shared__ float mx[2];
    if ((tid & 63) == 0) mx[tid >> 6] = m;
    __syncthreads();
    float M = fmaxf(mx[0], mx[1]);
    attnB[(b << 14) + (c << 7) + tid] = f2bf(fast_tanh(M - v));
}

// ---------------------------------------------------------------------------
// 7) QKV via MFMA. grid(64 ntiles, 4 b), block 256, 256 blocks.
//    Wave: n-sub = w>>1 (32 n), o-part = w&1 (tiles {0,1,2} or {3,4}).
// ---------------------------------------------------------------------------
__global__ __launch_bounds__(256) void qkv_mfma_kernel(
        const unsigned short* __restrict__ Wqkv, const float* __restrict__ biasAll,
        const unsigned short* __restrict__ fT,
        unsigned short* __restrict__ qT, unsigned short* __restrict__ kT,
        unsigned short* __restrict__ vB) {
    const int b = blockIdx.y, tid = threadIdx.x;
    const int w = tid >> 6, l31 = tid & 31, hi = (tid >> 5) & 1;
    const int n0 = (blockIdx.x << 6) + ((w >> 1) << 5);
    const int tstart = (w & 1) ? 3 : 0;
    const int tcnt   = (w & 1) ? 2 : 3;
    floatx16 acc[3];
#pragma unroll
    for (int t = 0; t < 3; ++t)
#pragma unroll
        for (int r = 0; r < 16; ++r) acc[t][r] = 0.f;

    for (int s = 0; s < 8; ++s) {
        const int k0 = (s << 4) + (hi << 3);
        short8 bf = *(const short8*)&fT[(((b << 12) + n0 + l31) << 7) + k0];
#pragma unroll
        for (int ti = 0; ti < 3; ++ti) {
            if (ti < tcnt) {
                short8 aw = *(const short8*)&Wqkv[((((tstart + ti) << 5) + l31) << 7) + k0];
                acc[ti] = __builtin_amdgcn_mfma_f32_32x32x16_bf16(aw, bf, acc[ti], 0, 0, 0);
            }
        }
    }
    const int n = n0 + l31;
#pragma unroll
    for (int ti = 0; ti < 3; ++ti) {
        if (ti >= tcnt) continue;
        const int t = tstart + ti;
#pragma unroll
        for (int r = 0; r < 16; ++r) {
            int o = (t << 5) + ROWMAP(r, hi);
            float val = acc[ti][r] + biasAll[o];
            if (t == 0) {
                if (o < 16) qT[(((b << 12) + n) << 4) + o] = f2bf(val);
                else        kT[(((b << 12) + n) << 4) + o - 16] = f2bf(val);
            } else if (o >= 32) {
                vB[(((b << 7) + o - 32) << 12) + n] = f2bf(val);
            }
        }
    }
}

// ---------------------------------------------------------------------------
// 8) PAM via MFMA 32x32x16 bf16 — wave-autonomous, 8-way n-split.
//    Wave = (32 m, all 128 c, n-eighth of 512). Hi-half swap via shfl_xor.
// grid(8 nh, 32, 4) = 1024 blocks, 4 blocks/CU, block 256.
// ---------------------------------------------------------------------------
__global__ __launch_bounds__(256, 4) void pam_mfma_kernel(
        const unsigned short* __restrict__ qT, const unsigned short* __restrict__ kT,
        const unsigned short* __restrict__ vB, unsigned short* __restrict__ pamP) {
    const int b = blockIdx.z, nh = blockIdx.x;
    const int tid = threadIdx.x;
    const int w = tid >> 6, lane = tid & 63, l31 = lane & 31, hi = lane >> 5;
    const int m0 = (blockIdx.y << 7) + (w << 5);

    short8 bq = *(const short8*)&qT[(((b << 12) + m0 + l31) << 4) + hi * 8];

    floatx16 acc[4], zero16;
#pragma unroll
    for (int r = 0; r < 16; ++r) {
        acc[0][r] = 0.f; acc[1][r] = 0.f; acc[2][r] = 0.f; acc[3][r] = 0.f;
        zero16[r] = 0.f;
    }

    const int nbase = nh << 9;
    short8 ak = *(const short8*)&kT[(((b << 12) + nbase + l31) << 4) + hi * 8];

    for (int nc = 0; nc < 16; ++nc) {
        const int na = nbase + (nc << 5);
        short8 av[8];
#pragma unroll
        for (int ct = 0; ct < 4; ++ct) {
            const unsigned short* vp = vB + (((b << 7) + (ct << 5) + l31) << 12) + na + hi * 8;
            av[2 * ct]     = *(const short8*)(vp);
            av[2 * ct + 1] = *(const short8*)(vp + 16);
        }
        floatx16 s = __builtin_amdgcn_mfma_f32_32x32x16_bf16(ak, bq, zero16, 0, 0, 0);
        if (nc < 15)
            ak = *(const short8*)&kT[(((b << 12) + na + 32 + l31) << 4) + hi * 8];
        unsigned p[8];
#pragma unroll
        for (int i = 0; i < 8; ++i) {
            float t0 = fast_tanh(s[2 * i]);
            float t1 = fast_tanh(s[2 * i + 1]);
            p[i] = (__float_as_uint(t1) & 0xFFFF0000u) | (__float_as_uint(t0) >> 16);
        }
        unsigned sh[8];
#pragma unroll
        for (int i = 0; i < 8; ++i) sh[i] = __shfl_xor(p[i], 32, 64);
        uint4v b1u, b2u;
        b1u[0] = hi ? sh[2] : p[0];
        b1u[1] = hi ? sh[3] : p[1];
        b1u[2] = hi ? p[2] : sh[0];
        b1u[3] = hi ? p[3] : sh[1];
        b2u[0] = hi ? sh[6] : p[4];
        b2u[1] = hi ? sh[7] : p[5];
        b2u[2] = hi ? p[6] : sh[4];
        b2u[3] = hi ? p[7] : sh[5];
        short8 B1 = __builtin_bit_cast(short8, b1u);
        short8 B2 = __builtin_bit_cast(short8, b2u);
#pragma unroll
        for (int ct = 0; ct < 4; ++ct) {
            acc[ct] = __builtin_amdgcn_mfma_f32_32x32x16_bf16(av[2 * ct], B1, acc[ct], 0, 0, 0);
            acc[ct] = __builtin_amdgcn_mfma_f32_32x32x16_bf16(av[2 * ct + 1], B2, acc[ct], 0, 0, 0);
        }
    }
    const int pbase = (((nh << 2) + b) << 19) + m0 + l31;
#pragma unroll
    for (int ct = 0; ct < 4; ++ct)
#pragma unroll
        for (int r = 0; r < 16; ++r) {
            int c = (ct << 5) + ROWMAP(r, hi);
            pamP[pbase + (c << 12)] = f2bf(acc[ct][r]);
        }
}

// ---------------------------------------------------------------------------
// 9) Combine: out = 3*feat + g_ca*(attn @ f) + g_pa*(sum_8 pamP).
// grid(64 mtiles, 4 b), block 256, 256 blocks.
// Wave: m-sub = w>>1 (32 m), c-half = w&1 (2 c-tiles).
// ---------------------------------------------------------------------------
__global__ __launch_bounds__(256) void combine_kernel(
        const unsigned short* __restrict__ attnB, const unsigned short* __restrict__ fT,
        const unsigned short* __restrict__ featB, const unsigned short* __restrict__ pamP,
        const float* __restrict__ gca, const float* __restrict__ gpa,
        float* __restrict__ out) {
    const int b = blockIdx.y, tid = threadIdx.x;
    const int w = tid >> 6, l31 = tid & 31, hi = (tid >> 5) & 1;
    const int m0 = (blockIdx.x << 6) + ((w >> 1) << 5);
    const int ct0 = (w & 1) << 1;
    floatx16 acc[2];
#pragma unroll
    for (int t = 0; t < 2; ++t)
#pragma unroll
        for (int r = 0; r < 16; ++r) acc[t][r] = 0.f;

    for (int s = 0; s < 8; ++s) {
        const int k0 = (s << 4) + (hi << 3);
        short8 bf = *(const short8*)&fT[(((b << 12) + m0 + l31) << 7) + k0];
        short8 a0 = *(const short8*)&attnB[(b << 14) + ((((ct0 + 0) << 5) + l31) << 7) + k0];
        short8 a1 = *(const short8*)&attnB[(b << 14) + ((((ct0 + 1) << 5) + l31) << 7) + k0];
        acc[0] = __builtin_amdgcn_mfma_f32_32x32x16_bf16(a0, bf, acc[0], 0, 0, 0);
        acc[1] = __builtin_amdgcn_mfma_f32_32x32x16_bf16(a1, bf, acc[1], 0, 0, 0);
    }
    const float gc = gca[0], gp = gpa[0];
    const int m = m0 + l31;
#pragma unroll
    for (int t = 0; t < 2; ++t)
#pragma unroll
        for (int r = 0; r < 16; ++r) {
            int c = ((ct0 + t) << 5) + ROWMAP(r, hi);
            int ci = (c << 12) + m;
            float p = 0.f;
#pragma unroll
            for (int sl = 0; sl < 8; ++sl)
                p += bf2f(pamP[(((sl << 2) + b) << 19) + ci]);
            float fb = bf2f(featB[(((b << 7) + c) << 12) + m]);
            out[(((b << 7) + c) << 12) + m] = 3.f * fb + gc * acc[t][r] + gp * p;
        }
}

// ---------------------------------------------------------------------------
extern "C" void kernel_launch(void* const* d_in, const int* in_sizes, int n_in,
                              void* d_out, int out_size, void* d_ws, size_t ws_size,
                              hipStream_t stream) {
    const float* x      = (const float*)d_in[0];
    const float* conv_w = (const float*)d_in[1];
    const float* bn_g   = (const float*)d_in[2];
    const float* bn_b   = (const float*)d_in[3];
    const float* q_w    = (const float*)d_in[4];
    const float* q_b    = (const float*)d_in[5];
    const float* k_w    = (const float*)d_in[6];
    const float* k_b    = (const float*)d_in[7];
    const float* v_w    = (const float*)d_in[8];
    const float* v_b    = (const float*)d_in[9];
    const float* gca    = (const float*)d_in[10];
    const float* gpa    = (const float*)d_in[11];
    float* out = (float*)d_out;

    float* ws = (float*)d_ws;
    // layout (floats) — dead-by-pam region first (aliased by pamP):
    float* convY  = ws;                                      // 2,097,152 f
    unsigned short* xTp = (unsigned short*)(ws + 2097152);   // 2,230,272 f
    float* ep     = ws + 4327424;                            // 4,194,304 f (64 slices)
    unsigned short* Wb2  = (unsigned short*)(ws + 8521728);  // 147,456 f
    unsigned short* Wqkv = (unsigned short*)(ws + 8669184);  // 10,240 f
    float* scale   = ws + 8679424;                           // 128
    float* shift   = ws + 8679552;                           // 128
    float* biasAll = ws + 8679680;                           // 192 (pad)
    // alive-through-pam region:
    unsigned short* attnB = (unsigned short*)(ws + 8679872);  // 32,768 f
    unsigned short* qT    = (unsigned short*)(ws + 8712640);  // 131,072 f
    unsigned short* kT    = (unsigned short*)(ws + 8843712);  // 131,072 f
    unsigned short* vB    = (unsigned short*)(ws + 8974784);  // 1,048,576 f
    unsigned short* featB = (unsigned short*)(ws + 10023360); // 1,048,576 f
    unsigned short* fT    = (unsigned short*)(ws + 11071936); // 1,048,576 f -> end 12,120,512 f
    // pamP bf16[8][4][128][4096] = 33.5 MB = 8,388,608 f, aliases the dead
    // region [0, 8,521,728) — convY/xTp/ep all dead before pam runs.
    unsigned short* pamP  = (unsigned short*)ws;

    xt_prep_kernel<<<dim3(4, 64, 4), 256, 0, stream>>>(x, xTp);
    prep_kernel<<<1232, 256, 0, stream>>>(conv_w, q_w, q_b, k_w, k_b, v_w, v_b,
                                          Wb2, Wqkv, biasAll);
    conv_mfma_kernel<<<dim3(4, 64, 4), 256, 0, stream>>>(xTp, Wb2, convY);
    bn_stats_kernel<<<128, 256, 0, stream>>>(convY, bn_g, bn_b, scale, shift);
    bn_apply_kernel<<<dim3(2, 64, 4), 256, 0, stream>>>(convY, scale, shift, featB, fT);
    cam_energy_mfma_kernel<<<dim3(64, 4), 256, 0, stream>>>(featB, ep);
    cam_attn_kernel<<<dim3(128, 4), 128, 0, stream>>>(ep, attnB);
    qkv_mfma_kernel<<<dim3(64, 4), 256, 0, stream>>>(Wqkv, biasAll, fT, qT, kT, vB);
    pam_mfma_kernel<<<dim3(8, 32, 4), 256, 0, stream>>>(qT, kT, vB, pamP);
    combine_kernel<<<dim3(64, 4), 256, 0, stream>>>(attnB, fT, featB, pamP, gca, gpa, out);
}

// Round 9
// 252.983 us; speedup vs baseline: 1.0803x; 1.0803x over previous
//
#include <hip/hip_runtime.h>
#include <math.h>

// Problem constants
#define BATCH 4
#define CIN   256
#define CCH   128      // Cout
#define HW    4096     // 64*64
#define CQK   16

using short8   = __attribute__((ext_vector_type(8))) short;
using floatx4  = __attribute__((ext_vector_type(4))) float;
using floatx16 = __attribute__((ext_vector_type(16))) float;
using uint4v   = __attribute__((ext_vector_type(4))) unsigned int;

// tanh via raw intrinsics: 1 v_mul + v_exp + v_add + v_rcp + v_fma.
// Saturates correctly: x->+inf => exp2->inf => rcp->0 => 1; x->-inf => -1.
__device__ __forceinline__ float fast_tanh(float x) {
    float e = __builtin_amdgcn_exp2f(x * 2.8853900817779268f);  // e^{2x}
    float r = __builtin_amdgcn_rcpf(e + 1.0f);
    return __builtin_fmaf(-2.0f, r, 1.0f);
}

__device__ __forceinline__ unsigned short f2bf(float f) {
    unsigned u = __float_as_uint(f);
    u += 0x7fff + ((u >> 16) & 1);   // RNE
    return (unsigned short)(u >> 16);
}

__device__ __forceinline__ float bf2f(unsigned short u) {
    return __uint_as_float(((unsigned)u) << 16);
}

// C/D row map for mfma_f32_32x32x16: row = (r&3) + 8*(r>>2) + 4*hi, col = lane&31
#define ROWMAP(r, hi) (((r) & 3) + (((r) >> 2) << 3) + ((hi) << 2))

#define XTP_ROW   (66 * 256)          // shorts per padded row
#define XTP_BATCH (66 * 66 * 256)     // shorts per batch

// ---------------------------------------------------------------------------
// 1) prep_all: [0,1024) x-transpose+halo; [1024,2176) conv weights;
//    [2176,2256) qkv weights; [2256] zero stats. grid 2257, block 256.
// ---------------------------------------------------------------------------
__global__ __launch_bounds__(256) void prep_all_kernel(
        const float* __restrict__ x, const float* __restrict__ w,
        const float* __restrict__ qw, const float* __restrict__ qb,
        const float* __restrict__ kw, const float* __restrict__ kb,
        const float* __restrict__ vw, const float* __restrict__ vb,
        unsigned short* __restrict__ xTp, unsigned short* __restrict__ Wb2,
        unsigned short* __restrict__ Wqkv, float* __restrict__ biasAll,
        float* __restrict__ statsS, float* __restrict__ statsQ) {
    const int bx = blockIdx.x, tid = threadIdx.x;
    if (bx < 1024) {
        __shared__ unsigned short lds[64][72];
        const int ci0 = (bx & 3) << 6, yr = (bx >> 2) & 63, b = bx >> 8;
        const int cir = tid >> 2, xc = tid & 3;
        const float* xp = x + (((b << 8) + ci0 + cir) << 12) + (yr << 6) + xc * 16;
#pragma unroll
        for (int j = 0; j < 4; ++j) {
            float4 v = *(const float4*)(xp + j * 4);
            int xi = xc * 16 + j * 4;
            lds[xi + 0][cir] = f2bf(v.x);
            lds[xi + 1][cir] = f2bf(v.y);
            lds[xi + 2][cir] = f2bf(v.z);
            lds[xi + 3][cir] = f2bf(v.w);
        }
        const short8 z8 = (short8){0,0,0,0,0,0,0,0};
        if (tid < 16) {
            int col = (tid >> 3) ? 65 : 0;
            int part = tid & 7;
            *(short8*)(xTp + b * XTP_BATCH + (yr + 1) * XTP_ROW + col * 256 +
                       ci0 + part * 8) = z8;
        }
        if (yr == 0 || yr == 63) {
            int row = (yr == 0) ? 0 : 65;
            for (int e = tid; e < 528; e += 256) {
                int xi = e >> 3, part = e & 7;
                *(short8*)(xTp + b * XTP_BATCH + row * XTP_ROW + xi * 256 +
                           ci0 + part * 8) = z8;
            }
        }
        __syncthreads();
        const int xr = tid >> 2, part = tid & 3;
        unsigned short* dst = xTp + b * XTP_BATCH + (yr + 1) * XTP_ROW +
                              (xr + 1) * 256 + ci0 + part * 16;
        *(short8*)(dst + 0) = *(const short8*)&lds[xr][part * 16 + 0];
        *(short8*)(dst + 8) = *(const short8*)&lds[xr][part * 16 + 8];
    } else if (bx < 2176) {
        int o = (bx - 1024) * 256 + tid;                 // < 294912
        int s   = o & 31;
        int co  = (o >> 5) & 127;
        int cc  = (o >> 12) & 7;
        int tap = o >> 15;
        int ci  = (cc << 5) + s;
        Wb2[o] = f2bf(w[co * 2304 + ci * 9 + tap]);
    } else if (bx < 2256) {
        int idx = (bx - 2176) * 256 + tid;               // < 20480
        int o = idx >> 7, c = idx & 127;
        float wv = (o < 16) ? qw[(o << 7) + c]
                 : (o < 32) ? kw[((o - 16) << 7) + c]
                            : vw[((o - 32) << 7) + c];
        Wqkv[idx] = f2bf(wv);
        if (idx < 160)
            biasAll[idx] = (idx < 16) ? qb[idx] : (idx < 32) ? kb[idx - 16] : vb[idx - 32];
    } else {
        if (tid < 128) { statsS[tid] = 0.f; statsQ[tid] = 0.f; }
    }
}

// ---------------------------------------------------------------------------
// 2) Conv implicit GEMM + fused BN-stat partials. Wave = 32 co x 64 px
//    (full row): 2 A + 4 B loads per 8 MFMA (halves L2 fragment traffic).
//    Epilogue: per-channel sum/sumsq reduced over px lanes -> atomicAdd.
// grid(2 co-groups, 64 y, 4 b) = 512 blocks, block 256 (2 waves... 4 waves?).
// Block = 2 waves? No: block 256 = 4 waves; co-groups of 32: cobase=cg*128?
// Here: block covers 128 co? grid.x=2 -> cg in {0,1}, cobase=(cg*2+w... )
// Simply: wave w (0..3) -> co base = cg*... use grid(1)? Keep: grid.x=1 won't
// fill. We use grid(2,64,4): co base = (cg<<6) + ((w&1)<<5), y-half? No —
// waves 0,1 -> co 0..63 of group, waves 2,3 duplicate px? Instead:
// co = cg*64 + (w&1)*32; px-half = (w>>1)*0... we keep 64px per wave and
// accept 2 waves doing co 0-63, 2 waves co 64-127 with cg selecting... 
// Final simple mapping: grid(2,64,4); wave w -> cobase = (cg? 0:0)*0 + w*32
// covers co 0..127 when cg==0?? -> use cg as x-half instead: px0 = cg*0.
// DECISION: block = 4 waves = co 0..127, full row; grid(1,64,4)=256 blocks.
// ---------------------------------------------------------------------------
__global__ __launch_bounds__(256) void conv_mfma_kernel(
        const unsigned short* __restrict__ xTp, const unsigned short* __restrict__ Wb2,
        float* __restrict__ y, float* __restrict__ statsS, float* __restrict__ statsQ) {
    const int tid = threadIdx.x;
    const int w = tid >> 6, lane = tid & 63, l15 = lane & 15, quad = lane >> 4;
    const int yr = blockIdx.x, b = blockIdx.y;
    const int cobase = w << 5;

    floatx4 acc[2][4];
#pragma unroll
    for (int i = 0; i < 2; ++i)
#pragma unroll
        for (int j = 0; j < 4; ++j) acc[i][j] = (floatx4){0.f, 0.f, 0.f, 0.f};

    const unsigned short* xb = xTp + b * XTP_BATCH + yr * XTP_ROW;
    const int aco0 = cobase + l15;

#pragma unroll
    for (int ky = 0; ky < 3; ++ky) {
#pragma unroll
        for (int kx = 0; kx < 3; ++kx) {
            const unsigned short* arow = Wb2 + ((ky * 3 + kx) << 15);
            const unsigned short* brow = xb + ky * XTP_ROW + kx * 256;
#pragma unroll
            for (int cc = 0; cc < 8; ++cc) {
                short8 a0 = *(const short8*)(arow + (((cc << 7) + aco0) << 5) + quad * 8);
                short8 a1 = *(const short8*)(arow + (((cc << 7) + aco0 + 16) << 5) + quad * 8);
#pragma unroll
                for (int ns = 0; ns < 4; ++ns) {
                    short8 bf = *(const short8*)(brow + (((ns << 4) + l15) << 8) + (cc << 5) + quad * 8);
                    acc[0][ns] = __builtin_amdgcn_mfma_f32_16x16x32_bf16(a0, bf, acc[0][ns], 0, 0, 0);
                    acc[1][ns] = __builtin_amdgcn_mfma_f32_16x16x32_bf16(a1, bf, acc[1][ns], 0, 0, 0);
                }
            }
        }
    }

    // stores
#pragma unroll
    for (int ms = 0; ms < 2; ++ms)
#pragma unroll
        for (int ns = 0; ns < 4; ++ns) {
            int px = (ns << 4) + l15;
#pragma unroll
            for (int r = 0; r < 4; ++r) {
                int co = cobase + ms * 16 + quad * 4 + r;
                y[(((b << 7) + co) << 12) + (yr << 6) + px] = acc[ms][ns][r];
            }
        }
    // fused BN stat partials: reduce over the 16 px lanes (l15), add 4 ns
#pragma unroll
    for (int ms = 0; ms < 2; ++ms)
#pragma unroll
        for (int r = 0; r < 4; ++r) {
            float s = acc[ms][0][r] + acc[ms][1][r] + acc[ms][2][r] + acc[ms][3][r];
            float q = acc[ms][0][r] * acc[ms][0][r] + acc[ms][1][r] * acc[ms][1][r] +
                      acc[ms][2][r] * acc[ms][2][r] + acc[ms][3][r] * acc[ms][3][r];
#pragma unroll
            for (int off = 1; off < 16; off <<= 1) {
                s += __shfl_xor(s, off);
                q += __shfl_xor(q, off);
            }
            if (l15 == 0) {
                int co = cobase + ms * 16 + quad * 4 + r;
                atomicAdd(&statsS[co], s);
                atomicAdd(&statsQ[co], q);
            }
        }
}

// ---------------------------------------------------------------------------
// 3) BN apply + ReLU (scale computed inline from sums) -> featB + fT.
// grid(2, 64, 4), block 256
// ---------------------------------------------------------------------------
__global__ __launch_bounds__(256) void bn_apply_kernel(
        const float* __restrict__ y, const float* __restrict__ statsS,
        const float* __restrict__ statsQ, const float* __restrict__ gamma,
        const float* __restrict__ beta, unsigned short* __restrict__ featB,
        unsigned short* __restrict__ fT) {
    __shared__ unsigned short lds[64][72];
    const int tid = threadIdx.x;
    const int c0 = blockIdx.x * 64, n0 = blockIdx.y * 64, b = blockIdx.z;
    const int cir = tid >> 2, xc = tid & 3;
    const int c = c0 + cir;
    const float S = statsS[c], Q = statsQ[c];
    const float mean = S * (1.f / 16384.f);
    const float var  = Q * (1.f / 16384.f) - mean * mean;
    const float rstd = rsqrtf(var + 1e-5f);
    const float sc = gamma[c] * rstd;
    const float sh = beta[c] - mean * sc;
    const float* yp = y + (((b << 7) + c) << 12) + n0 + xc * 16;
    unsigned short* fp = featB + (((b << 7) + c) << 12) + n0 + xc * 16;
#pragma unroll
    for (int j = 0; j < 4; ++j) {
        float4 v = *(const float4*)(yp + j * 4);
        ushort4 o;
        o.x = f2bf(fmaxf(fmaf(v.x, sc, sh), 0.f));
        o.y = f2bf(fmaxf(fmaf(v.y, sc, sh), 0.f));
        o.z = f2bf(fmaxf(fmaf(v.z, sc, sh), 0.f));
        o.w = f2bf(fmaxf(fmaf(v.w, sc, sh), 0.f));
        *(ushort4*)(fp + j * 4) = o;
        int ni = xc * 16 + j * 4;
        lds[ni + 0][cir] = o.x;
        lds[ni + 1][cir] = o.y;
        lds[ni + 2][cir] = o.z;
        lds[ni + 3][cir] = o.w;
    }
    __syncthreads();
    const int nr = tid >> 2, part = tid & 3;
    unsigned short* dst = fT + (((b << 12) + n0 + nr) << 7) + c0 + part * 16;
    *(short8*)(dst + 0) = *(const short8*)&lds[nr][part * 16 + 0];
    *(short8*)(dst + 8) = *(const short8*)&lds[nr][part * 16 + 8];
}

// ---------------------------------------------------------------------------
// 4) Fused cam_energy (blocks [0,256)) + qkv (blocks [256,512)). grid 512.
// ---------------------------------------------------------------------------
__global__ __launch_bounds__(256) void camqkv_kernel(
        const unsigned short* __restrict__ featB, float* __restrict__ ep,
        const unsigned short* __restrict__ Wqkv, const float* __restrict__ biasAll,
        const unsigned short* __restrict__ fT,
        unsigned short* __restrict__ qT, unsigned short* __restrict__ kT,
        unsigned short* __restrict__ vB) {
    const int bx = blockIdx.x, tid = threadIdx.x;
    const int l31 = tid & 31, hi = (tid >> 5) & 1;
    if (bx < 256) {
        // cam_energy: split-K 64, kc = bx&63, b = bx>>6
        const int kc = bx & 63, b = bx >> 6, wv = tid >> 6;
        floatx16 acc[4];
#pragma unroll
        for (int t = 0; t < 4; ++t)
#pragma unroll
            for (int r = 0; r < 16; ++r) acc[t][r] = 0.f;
        for (int s = 0; s < 4; ++s) {
            const int k0 = (kc << 6) + (s << 4) + (hi << 3);
            short8 fr = *(const short8*)&featB[(((b << 7) + (wv << 5) + l31) << 12) + k0];
            short8 fc0 = *(const short8*)&featB[(((b << 7) +  0 + l31) << 12) + k0];
            short8 fc1 = *(const short8*)&featB[(((b << 7) + 32 + l31) << 12) + k0];
            short8 fc2 = *(const short8*)&featB[(((b << 7) + 64 + l31) << 12) + k0];
            short8 fc3 = *(const short8*)&featB[(((b << 7) + 96 + l31) << 12) + k0];
            acc[0] = __builtin_amdgcn_mfma_f32_32x32x16_bf16(fr, fc0, acc[0], 0, 0, 0);
            acc[1] = __builtin_amdgcn_mfma_f32_32x32x16_bf16(fr, fc1, acc[1], 0, 0, 0);
            acc[2] = __builtin_amdgcn_mfma_f32_32x32x16_bf16(fr, fc2, acc[2], 0, 0, 0);
            acc[3] = __builtin_amdgcn_mfma_f32_32x32x16_bf16(fr, fc3, acc[3], 0, 0, 0);
        }
#pragma unroll
        for (int t = 0; t < 4; ++t)
#pragma unroll
            for (int r = 0; r < 16; ++r) {
                int c = ((tid >> 6) << 5) + ROWMAP(r, hi);
                int d = (t << 5) + l31;
                ep[(((kc << 2) + b) << 14) + (c << 7) + d] = acc[t][r];
            }
    } else {
        // qkv: bi = bx-256; ntile = bi&63, b = bi>>6
        const int bi = bx - 256, b = bi >> 6, w = tid >> 6;
        const int n0 = ((bi & 63) << 6) + ((w >> 1) << 5);
        const int tstart = (w & 1) ? 3 : 0;
        const int tcnt   = (w & 1) ? 2 : 3;
        floatx16 acc[3];
#pragma unroll
        for (int t = 0; t < 3; ++t)
#pragma unroll
            for (int r = 0; r < 16; ++r) acc[t][r] = 0.f;
        for (int s = 0; s < 8; ++s) {
            const int k0 = (s << 4) + (hi << 3);
            short8 bf = *(const short8*)&fT[(((b << 12) + n0 + l31) << 7) + k0];
#pragma unroll
            for (int ti = 0; ti < 3; ++ti) {
                if (ti < tcnt) {
                    short8 aw = *(const short8*)&Wqkv[((((tstart + ti) << 5) + l31) << 7) + k0];
                    acc[ti] = __builtin_amdgcn_mfma_f32_32x32x16_bf16(aw, bf, acc[ti], 0, 0, 0);
                }
            }
        }
        const int n = n0 + l31;
#pragma unroll
        for (int ti = 0; ti < 3; ++ti) {
            if (ti >= tcnt) continue;
            const int t = tstart + ti;
#pragma unroll
            for (int r = 0; r < 16; ++r) {
                int o = (t << 5) + ROWMAP(r, hi);
                float val = acc[ti][r] + biasAll[o];
                if (t == 0) {
                    if (o < 16) qT[(((b << 12) + n) << 4) + o] = f2bf(val);
                    else        kT[(((b << 12) + n) << 4) + o - 16] = f2bf(val);
                } else if (o >= 32) {
                    vB[(((b << 7) + o - 32) << 12) + n] = f2bf(val);
                }
            }
        }
    }
}

// ---------------------------------------------------------------------------
// 5) Fused pam (blocks [0,512)) + cam_attn (blocks [512,768)). grid 768.
//    pam: wave-autonomous, 4-way n-split, shfl hi-half swap, fast tanh.
// ---------------------------------------------------------------------------
__global__ __launch_bounds__(256) void pam_attn_kernel(
        const unsigned short* __restrict__ qT, const unsigned short* __restrict__ kT,
        const unsigned short* __restrict__ vB, unsigned short* __restrict__ pamP,
        const float* __restrict__ ep, unsigned short* __restrict__ attnB) {
    const int bx = blockIdx.x, tid = threadIdx.x;
    if (bx < 512) {
        const int nh = bx & 3, b = bx >> 7;
        const int w = tid >> 6, lane = tid & 63, l31 = lane & 31, hi = lane >> 5;
        const int m0 = (((bx >> 2) & 31) << 7) + (w << 5);

        short8 bq = *(const short8*)&qT[(((b << 12) + m0 + l31) << 4) + hi * 8];

        floatx16 acc[4], zero16;
#pragma unroll
        for (int r = 0; r < 16; ++r) {
            acc[0][r] = 0.f; acc[1][r] = 0.f; acc[2][r] = 0.f; acc[3][r] = 0.f;
            zero16[r] = 0.f;
        }

        const int nbase = nh << 10;
        short8 ak = *(const short8*)&kT[(((b << 12) + nbase + l31) << 4) + hi * 8];

        for (int nc = 0; nc < 32; ++nc) {
            const int na = nbase + (nc << 5);
            short8 av[8];
#pragma unroll
            for (int ct = 0; ct < 4; ++ct) {
                const unsigned short* vp = vB + (((b << 7) + (ct << 5) + l31) << 12) + na + hi * 8;
                av[2 * ct]     = *(const short8*)(vp);
                av[2 * ct + 1] = *(const short8*)(vp + 16);
            }
            floatx16 s = __builtin_amdgcn_mfma_f32_32x32x16_bf16(ak, bq, zero16, 0, 0, 0);
            if (nc < 31)
                ak = *(const short8*)&kT[(((b << 12) + na + 32 + l31) << 4) + hi * 8];
            unsigned p[8];
#pragma unroll
            for (int i = 0; i < 8; ++i) {
                float t0 = fast_tanh(s[2 * i]);
                float t1 = fast_tanh(s[2 * i + 1]);
                p[i] = (__float_as_uint(t1) & 0xFFFF0000u) | (__float_as_uint(t0) >> 16);
            }
            unsigned sh[8];
#pragma unroll
            for (int i = 0; i < 8; ++i) sh[i] = __shfl_xor(p[i], 32, 64);
            uint4v b1u, b2u;
            b1u[0] = hi ? sh[2] : p[0];
            b1u[1] = hi ? sh[3] : p[1];
            b1u[2] = hi ? p[2] : sh[0];
            b1u[3] = hi ? p[3] : sh[1];
            b2u[0] = hi ? sh[6] : p[4];
            b2u[1] = hi ? sh[7] : p[5];
            b2u[2] = hi ? p[6] : sh[4];
            b2u[3] = hi ? p[7] : sh[5];
            short8 B1 = __builtin_bit_cast(short8, b1u);
            short8 B2 = __builtin_bit_cast(short8, b2u);
#pragma unroll
            for (int ct = 0; ct < 4; ++ct) {
                acc[ct] = __builtin_amdgcn_mfma_f32_32x32x16_bf16(av[2 * ct], B1, acc[ct], 0, 0, 0);
                acc[ct] = __builtin_amdgcn_mfma_f32_32x32x16_bf16(av[2 * ct + 1], B2, acc[ct], 0, 0, 0);
            }
        }
        const int pbase = (((nh << 2) + b) << 19) + m0 + l31;
#pragma unroll
        for (int ct = 0; ct < 4; ++ct)
#pragma unroll
            for (int r = 0; r < 16; ++r) {
                int c = (ct << 5) + ROWMAP(r, hi);
                pamP[pbase + (c << 12)] = f2bf(acc[ct][r]);
            }
    } else {
        // cam_attn: bi = bx-512 (0..255): b = bi>>6, 2 rows per block
        const int bi = bx - 512, b = bi >> 6;
        const int half = tid >> 7, t = tid & 127;
        const int c = ((bi & 63) << 1) + half;
        float v = 0.f;
#pragma unroll 8
        for (int s = 0; s < 64; ++s)
            v += ep[(((s << 2) + b) << 14) + (c << 7) + t];
        float m = v;
        for (int off = 32; off; off >>= 1) m = fmaxf(m, __shfl_down(m, off));
        __shared__ float mx[4];
        if ((tid & 63) == 0) mx[tid >> 6] = m;
        __syncthreads();
        float M = fmaxf(mx[half << 1], mx[(half << 1) + 1]);
        attnB[(b << 14) + (c << 7) + t] = f2bf(fast_tanh(M - v));
    }
}

// ---------------------------------------------------------------------------
// 6) Combine: out = 3*feat + g_ca*(attn @ f) + g_pa*(sum_4 pamP).
// grid(64, 4), block 256.
// ---------------------------------------------------------------------------
__global__ __launch_bounds__(256) void combine_kernel(
        const unsigned short* __restrict__ attnB, const unsigned short* __restrict__ fT,
        const unsigned short* __restrict__ featB, const unsigned short* __restrict__ pamP,
        const float* __restrict__ gca, const float* __restrict__ gpa,
        float* __restrict__ out) {
    const int b = blockIdx.y, tid = threadIdx.x;
    const int w = tid >> 6, l31 = tid & 31, hi = (tid >> 5) & 1;
    const int m0 = (blockIdx.x << 6) + ((w >> 1) << 5);
    const int ct0 = (w & 1) << 1;
    floatx16 acc[2];
#pragma unroll
    for (int t = 0; t < 2; ++t)
#pragma unroll
        for (int r = 0; r < 16; ++r) acc[t][r] = 0.f;

    for (int s = 0; s < 8; ++s) {
        const int k0 = (s << 4) + (hi << 3);
        short8 bf = *(const short8*)&fT[(((b << 12) + m0 + l31) << 7) + k0];
        short8 a0 = *(const short8*)&attnB[(b << 14) + ((((ct0 + 0) << 5) + l31) << 7) + k0];
        short8 a1 = *(const short8*)&attnB[(b << 14) + ((((ct0 + 1) << 5) + l31) << 7) + k0];
        acc[0] = __builtin_amdgcn_mfma_f32_32x32x16_bf16(a0, bf, acc[0], 0, 0, 0);
        acc[1] = __builtin_amdgcn_mfma_f32_32x32x16_bf16(a1, bf, acc[1], 0, 0, 0);
    }
    const float gc = gca[0], gp = gpa[0];
    const int m = m0 + l31;
#pragma unroll
    for (int t = 0; t < 2; ++t)
#pragma unroll
        for (int r = 0; r < 16; ++r) {
            int c = ((ct0 + t) << 5) + ROWMAP(r, hi);
            int ci = (c << 12) + m;
            float p = bf2f(pamP[((0 * 4 + b) << 19) + ci]) +
                      bf2f(pamP[((1 * 4 + b) << 19) + ci]) +
                      bf2f(pamP[((2 * 4 + b) << 19) + ci]) +
                      bf2f(pamP[((3 * 4 + b) << 19) + ci]);
            float fb = bf2f(featB[(((b << 7) + c) << 12) + m]);
            out[(((b << 7) + c) << 12) + m] = 3.f * fb + gc * acc[t][r] + gp * p;
        }
}

// ---------------------------------------------------------------------------
extern "C" void kernel_launch(void* const* d_in, const int* in_sizes, int n_in,
                              void* d_out, int out_size, void* d_ws, size_t ws_size,
                              hipStream_t stream) {
    const float* x      = (const float*)d_in[0];
    const float* conv_w = (const float*)d_in[1];
    const float* bn_g   = (const float*)d_in[2];
    const float* bn_b   = (const float*)d_in[3];
    const float* q_w    = (const float*)d_in[4];
    const float* q_b    = (const float*)d_in[5];
    const float* k_w    = (const float*)d_in[6];
    const float* k_b    = (const float*)d_in[7];
    const float* v_w    = (const float*)d_in[8];
    const float* v_b    = (const float*)d_in[9];
    const float* gca    = (const float*)d_in[10];
    const float* gpa    = (const float*)d_in[11];
    float* out = (float*)d_out;

    float* ws = (float*)d_ws;
    // dead-by-pam region (aliased by pamP, 4 slices = 4,194,304 f):
    float* convY  = ws;                                      // 2,097,152 f
    unsigned short* xTp = (unsigned short*)(ws + 2097152);   // 2,230,272 f
    // alive-through-pam region:
    float* ep     = ws + 4327424;                            // 4,194,304 f (64 slices)
    unsigned short* Wb2  = (unsigned short*)(ws + 8521728);  // 147,456 f
    unsigned short* Wqkv = (unsigned short*)(ws + 8669184);  // 10,240 f
    float* statsS  = ws + 8679424;                           // 128
    float* statsQ  = ws + 8679552;                           // 128
    float* biasAll = ws + 8679680;                           // 192 (pad)
    unsigned short* attnB = (unsigned short*)(ws + 8679872);  // 32,768 f
    unsigned short* qT    = (unsigned short*)(ws + 8712640);  // 131,072 f
    unsigned short* kT    = (unsigned short*)(ws + 8843712);  // 131,072 f
    unsigned short* vB    = (unsigned short*)(ws + 8974784);  // 1,048,576 f
    unsigned short* featB = (unsigned short*)(ws + 10023360); // 1,048,576 f
    unsigned short* fT    = (unsigned short*)(ws + 11071936); // 1,048,576 f -> 12,120,512 f
    // pamP bf16[4][4][128][4096] = 8,388,608 sh = 4,194,304 f, aliases
    // [0, 4,327,424) = convY+xTp (dead before pam; ep stays clear).
    unsigned short* pamP  = (unsigned short*)ws;

    prep_all_kernel<<<2257, 256, 0, stream>>>(x, conv_w, q_w, q_b, k_w, k_b,
                                              v_w, v_b, xTp, Wb2, Wqkv, biasAll,
                                              statsS, statsQ);
    conv_mfma_kernel<<<dim3(64, 4), 256, 0, stream>>>(xTp, Wb2, convY, statsS, statsQ);
    bn_apply_kernel<<<dim3(2, 64, 4), 256, 0, stream>>>(convY, statsS, statsQ,
                                                        bn_g, bn_b, featB, fT);
    camqkv_kernel<<<512, 256, 0, stream>>>(featB, ep, Wqkv, biasAll, fT, qT, kT, vB);
    pam_attn_kernel<<<768, 256, 0, stream>>>(qT, kT, vB, pamP, ep, attnB);
    combine_kernel<<<dim3(64, 4), 256, 0, stream>>>(attnB, fT, featB, pamP, gca, gpa, out);
}